// Round 5
// baseline (240.210 us; speedup 1.0000x reference)
//
#include <hip/hip_runtime.h>
#include <stdint.h>

// ---- problem constants ----
// z: [32][256][32][32] fp32, kappa:[1], codebook:[512][256], gumbel:[32768][512]
// out: z_to_decoder [32][256][32][32] (8388608) + loss + perplexity
// Round 5 geometry: 2048 blocks x 128 threads, 16 rows/block, 8 blocks/CU.

typedef float v4f __attribute__((ext_vector_type(4)));
typedef short v8s __attribute__((ext_vector_type(8)));
typedef short v4s __attribute__((ext_vector_type(4)));

#define ZA_STR 264   // shorts; za row stride
#define L2_STR 520   // shorts; e/er row stride (1040B, 16B aligned)

__device__ __forceinline__ uint16_t f2bf(float x) {
  uint32_t u = __float_as_uint(x);
  u = u + 0x7fffu + ((u >> 16) & 1u);   // round-to-nearest-even
  return (uint16_t)(u >> 16);
}
__device__ __forceinline__ float bf2f(uint16_t h) {
  return __uint_as_float(((uint32_t)h) << 16);
}

// ---- workspace layout (bytes) ----
// [0]       cbn2 bf16 [128K]  frag-permuted normalized codebook, GEMM1 B
//           addr = ((ks*16+ct)*2+w)*512 + lane*8 + j ; code=w*256+ct*16+m, k=ks*32+q*8+j
// [262144]  cbt2 bf16 [128K]  frag-permuted transposed codebook, GEMM2 B
//           addr = ((cc*8+nt)*2+w)*512 + lane*8 + j ; d=w*128+nt*16+m, k=cc*32+q*8+j
// [524288]  shadow fp32 [16][512]  avg_probs partial accumulators
// [557056]  scal fp32 [3]: {sum p*logp, sum z^2, sum er*(l2+mx)/Se}
// [557072]  rnorm fp32 [512]

__global__ __launch_bounds__(64) void vq_prep0(const float* __restrict__ cb,
                                               char* __restrict__ ws) {
  const int blk = blockIdx.x, t = threadIdx.x;
  float* shadow = (float*)(ws + 524288);
  float* scal   = (float*)(ws + 557056);
  float* rnorm  = (float*)(ws + 557072);
  if (blk < 512) {
    float s = 0.f;
#pragma unroll
    for (int i = 0; i < 4; i++) { const float v = cb[blk * 256 + t + 64 * i]; s += v * v; }
#pragma unroll
    for (int mm = 1; mm < 64; mm <<= 1) s += __shfl_xor(s, mm, 64);
    if (t == 0) rnorm[blk] = 1.0f / sqrtf(s);
  } else if (blk < 528) {
    const int j = blk - 512;
#pragma unroll
    for (int i = 0; i < 8; i++) shadow[j * 512 + t + 64 * i] = 0.f;
  } else {
    if (t < 3) scal[t] = 0.f;
  }
}

__global__ __launch_bounds__(256) void vq_prep1(const float* __restrict__ cb,
                                                char* __restrict__ ws) {
  const int b = blockIdx.x, t = threadIdx.x;
  uint16_t* cbn2 = (uint16_t*)ws;
  uint16_t* cbt2 = (uint16_t*)(ws + 262144);
  const float* rnorm = (const float*)(ws + 557072);
  union { v8s v; uint16_t u[8]; } pk;
  if (b < 64) {
    const int g = b * 256 + t;           // code x d-chunk(8)
    const int code = g >> 5, dch = g & 31;
    const float rn = rnorm[code];
    const float4 f0 = *(const float4*)(cb + code * 256 + dch * 8);
    const float4 f1 = *(const float4*)(cb + code * 256 + dch * 8 + 4);
    pk.u[0] = f2bf(f0.x * rn); pk.u[1] = f2bf(f0.y * rn);
    pk.u[2] = f2bf(f0.z * rn); pk.u[3] = f2bf(f0.w * rn);
    pk.u[4] = f2bf(f1.x * rn); pk.u[5] = f2bf(f1.y * rn);
    pk.u[6] = f2bf(f1.z * rn); pk.u[7] = f2bf(f1.w * rn);
    const int w2 = code >> 8, ct = (code >> 4) & 15, mcol = code & 15;
    const int ks = dch >> 2, q3 = dch & 3;          // d = ks*32 + q3*8 + j
    *(v8s*)(cbn2 + ((((ks << 4) + ct) * 2 + w2) << 9) + (((q3 << 4) + mcol) << 3)) = pk.v;
  } else {
    const int g = (b - 64) * 256 + t;    // cgroup(8 codes) x d
    const int cgroup = g >> 8, d = g & 255;
#pragma unroll
    for (int j = 0; j < 8; j++) {
      const int c = cgroup * 8 + j;
      pk.u[j] = f2bf(cb[c * 256 + d] * rnorm[c]);
    }
    const int cc = cgroup >> 2, qq = cgroup & 3;    // k = cc*32 + qq*8 + j
    const int wd = d >> 7, nt = (d >> 4) & 7, md = d & 15;
    *(v8s*)(cbt2 + ((((cc << 3) + nt) * 2 + wd) << 9) + (((qq << 4) + md) << 3)) = pk.v;
  }
}

__global__ __launch_bounds__(128, 4) void vq_main(const float* __restrict__ z,
                                                  const float* __restrict__ kappa,
                                                  const float* __restrict__ gum,
                                                  char* __restrict__ ws,
                                                  float* __restrict__ out) {
  __shared__ char s_A[16640];   // za short[16][264] -> e/er short[16][520] (in-place)
  __shared__ float s_pm[32], s_pS[32], s_pT[32];
  __shared__ float s_M[16], s_rS[16], s_kd[16], s_rSe[16], s_red[2];

  const int t = threadIdx.x;
  const int w = t >> 6, lane = t & 63, q = lane >> 4, m = lane & 15;
  const int bi = blockIdx.x, b = bi >> 6, wh0 = (bi & 63) << 4;
  const int R0 = bi << 4;

  const uint16_t* cbn2 = (const uint16_t*)ws;
  const uint16_t* cbt2 = (const uint16_t*)(ws + 262144);
  float* shadow = (float*)(ws + 524288);
  float* scal   = (float*)(ws + 557056);

  uint16_t* za  = (uint16_t*)s_A;
  uint16_t* l2s = (uint16_t*)s_A;

  const float kq = fminf(fmaxf(kappa[0], 1e-5f), 1e5f);

  // transform-phase mapping (also used for gumbel prefetch)
  const int row = t >> 3, c4 = (t & 7) << 2;
  const float* gbase = gum + (size_t)(R0 + row) * 512 + c4;

  // ---------- staging: z -> LDS bf16 (A-layout) fused with sum(z^2) ----------
  {
    float zs = 0.f;
    const int whb = (t & 3) << 2, dT = t >> 2;
    const float* zb = z + ((size_t)b << 18) + wh0 + whb;
#pragma unroll
    for (int s = 0; s < 8; s++) {
      const int d = dT + (s << 5);
      const float4 v = *(const float4*)(zb + (d << 10));
      zs += v.x * v.x + v.y * v.y + v.z * v.z + v.w * v.w;
      za[(whb + 0) * ZA_STR + d] = f2bf(v.x);
      za[(whb + 1) * ZA_STR + d] = f2bf(v.y);
      za[(whb + 2) * ZA_STR + d] = f2bf(v.z);
      za[(whb + 3) * ZA_STR + d] = f2bf(v.w);
    }
#pragma unroll
    for (int mm = 1; mm < 64; mm <<= 1) zs += __shfl_xor(zs, mm, 64);
    if (lane == 0) s_red[w] = zs;
  }

  // gumbel rolling prefetch, depth 4 (latency covered by GEMM1 + softmax)
  float4 gq[4];
#pragma unroll
  for (int i = 0; i < 4; i++) gq[i] = *(const float4*)(gbase + (i << 5));

  __syncthreads();  // B1
  if (t == 0) atomicAdd(&scal[1], s_red[0] + s_red[1]);

  // ---------- GEMM1: logits[16][512] = kq * z @ cbn^T ; wave w covers 256 codes ----------
  v4f acc[16];
#pragma unroll
  for (int i = 0; i < 16; i++) acc[i] = (v4f)0.f;
  {
    const uint16_t* bp = cbn2 + (w << 9) + (lane << 3);
    const uint16_t* ap = za + m * ZA_STR;
#pragma unroll
    for (int ks = 0; ks < 8; ks++) {
      const v8s a = *(const v8s*)(ap + (ks << 5) + (q << 3));
#pragma unroll
      for (int ct = 0; ct < 16; ct++) {
        const v8s bf = *(const v8s*)(bp + (((ks << 4) + ct) << 10));
        acc[ct] = __builtin_amdgcn_mfma_f32_16x16x32_bf16(a, bf, acc[ct], 0, 0, 0);
      }
    }
  }
#pragma unroll
  for (int i = 0; i < 16; i++) acc[i] *= kq;

  // ---------- per-wave per-row softmax stats (rows r=q*4+reg, cols ct*16+m) ----------
  {
#pragma unroll
    for (int reg = 0; reg < 4; reg++) {
      float mx = -1e30f;
#pragma unroll
      for (int ct = 0; ct < 16; ct++) mx = fmaxf(mx, acc[ct][reg]);
#pragma unroll
      for (int mm = 1; mm < 16; mm <<= 1) mx = fmaxf(mx, __shfl_xor(mx, mm, 64));
      float S = 0.f, T = 0.f;
#pragma unroll
      for (int ct = 0; ct < 16; ct++) {
        const float d = acc[ct][reg] - mx;
        const float e = __expf(d);
        S += e; T += d * e;
      }
#pragma unroll
      for (int mm = 1; mm < 16; mm <<= 1) { S += __shfl_xor(S, mm, 64); T += __shfl_xor(T, mm, 64); }
      if (m == 0) {
        const int r = q * 4 + reg;
        s_pm[(w << 4) + r] = mx; s_pS[(w << 4) + r] = S; s_pT[(w << 4) + r] = T;
      }
    }
  }
  __syncthreads();  // B2
  if (t < 16) {  // merge 2 wave-partials per row (online-softmax merge)
    const float m0 = s_pm[t], m1 = s_pm[16 + t];
    const float M = fmaxf(m0, m1);
    const float a0 = __expf(m0 - M), a1 = __expf(m1 - M);
    const float S = s_pS[t] * a0 + s_pS[16 + t] * a1;
    const float T = (s_pT[t] + (m0 - M) * s_pS[t]) * a0
                  + (s_pT[16 + t] + (m1 - M) * s_pS[16 + t]) * a1;
    const float rS = 1.0f / S;
    s_M[t] = M; s_rS[t] = rS; s_kd[t] = T * rS - __logf(S);
  }
  __syncthreads();  // B3

  // ---------- pass2: p column sums + e=exp(l2) -> LDS bf16 (za is dead) ----------
  {
    const int c0 = w << 8;
    float colacc[16];
#pragma unroll
    for (int i = 0; i < 16; i++) colacc[i] = 0.f;
#pragma unroll
    for (int reg = 0; reg < 4; reg++) {
      const int r = q * 4 + reg;
      const float Mr = s_M[r], rSr = s_rS[r];
      uint16_t* lrow = l2s + r * L2_STR + c0 + m;
#pragma unroll
      for (int ct = 0; ct < 16; ct++) {
        const float d = fmaxf(acc[ct][reg] - Mr, -50.0f);
        const float e = __expf(d);
        colacc[ct] += e * rSr;
        lrow[ct << 4] = f2bf(e);     // store e; er=(e/L)^2 in transform
      }
    }
#pragma unroll
    for (int i = 0; i < 16; i++) {
      colacc[i] += __shfl_xor(colacc[i], 16, 64);
      colacc[i] += __shfl_xor(colacc[i], 32, 64);
    }
    if (q == 0) {
      float* sh = shadow + ((bi & 15) << 9) + c0 + m;
#pragma unroll
      for (int i = 0; i < 16; i++) atomicAdd(&sh[i << 4], colacc[i]);
    }
    if (w == 0) {  // kld_discrete partial: one atomic per block
      float kd = (lane < 16) ? s_kd[lane] : 0.f;
#pragma unroll
      for (int mm = 1; mm < 64; mm <<= 1) kd += __shfl_xor(kd, mm, 64);
      if (lane == 0) atomicAdd(&scal[0], kd);
    }
  }
  __syncthreads();  // B4

  // ---------- in-place transform: e -> er = (e/L)^2 ; se, ce per row ----------
  {
    const float mxr = s_M[row];
    float se = 0.f, ce = 0.f;
    union { v4s v; uint16_t h[4]; } ev, rv;
#pragma unroll
    for (int i = 0; i < 16; i++) {
      const float4 u = gq[i & 3];
      const float uu[4] = {u.x, u.y, u.z, u.w};
      ev.v = *(const v4s*)(l2s + row * L2_STR + (i << 5) + c4);
      if (i < 12) gq[i & 3] = *(const float4*)(gbase + ((i + 4) << 5));
#pragma unroll
      for (int j = 0; j < 4; j++) {
        const float e = bf2f(ev.h[j]);
        const float L = -__logf(uu[j] + 1e-10f) + 1e-10f;
        const float f = __fdividef(e, L);
        const float er = f * f;                 // exp((l2+g)/T), T=0.5
        se += er;
        ce += er * (__logf(e) + mxr);           // er * raw_logit (analytic z.zq)
        rv.h[j] = f2bf(er);
      }
      *(v4s*)(l2s + row * L2_STR + (i << 5) + c4) = rv.v;
    }
#pragma unroll
    for (int mm = 1; mm < 8; mm <<= 1) { se += __shfl_xor(se, mm, 64); ce += __shfl_xor(ce, mm, 64); }
    float cr = ((t & 7) == 0) ? (ce / se) : 0.f;
#pragma unroll
    for (int mm = 8; mm < 64; mm <<= 1) cr += __shfl_xor(cr, mm, 64);
    if (lane == 0) s_red[w] = cr;
    if ((t & 7) == 0) s_rSe[row] = 1.0f / se;
  }
  __syncthreads();  // B5 — last barrier; MFMA stream below is barrier-free
  if (t == 0) atomicAdd(&scal[2], s_red[0] + s_red[1]);

  // ---------- GEMM2: zq[16][256] = (er @ cbn) / Se ; wave w covers 128 d-cols ----------
  v4f acc2[8];
#pragma unroll
  for (int i = 0; i < 8; i++) acc2[i] = (v4f)0.f;
  {
    const uint16_t* a2p = l2s + m * L2_STR;
    const uint16_t* bp2 = cbt2 + (w << 9) + (lane << 3);
#pragma unroll
    for (int cc = 0; cc < 16; cc++) {
      const v8s a = *(const v8s*)(a2p + (cc << 5) + (q << 3));
#pragma unroll
      for (int nt = 0; nt < 8; nt++) {
        const v8s bf = *(const v8s*)(bp2 + ((((cc << 3) + nt)) << 10));
        acc2[nt] = __builtin_amdgcn_mfma_f32_16x16x32_bf16(a, bf, acc2[nt], 0, 0, 0);
      }
    }
  }

  // ---------- epilogue: float4 stores (4 consecutive wh per lane-quad) ----------
  {
    float* ob = out + ((size_t)b << 18) + wh0 + (q << 2);
    float rs[4];
#pragma unroll
    for (int reg = 0; reg < 4; reg++) rs[reg] = s_rSe[(q << 2) + reg];
#pragma unroll
    for (int nt = 0; nt < 8; nt++) {
      const int d = (w << 7) + (nt << 4) + m;
      float4 v;
      v.x = acc2[nt][0] * rs[0]; v.y = acc2[nt][1] * rs[1];
      v.z = acc2[nt][2] * rs[2]; v.w = acc2[nt][3] * rs[3];
      *(float4*)(ob + (d << 10)) = v;
    }
  }
}

__global__ __launch_bounds__(512) void vq_final(const float* __restrict__ kappa,
                                                char* __restrict__ ws,
                                                float* __restrict__ out) {
  __shared__ float red[8];
  const int t = threadIdx.x;
  const float* shadow = (const float*)(ws + 524288);
  const float* scal   = (const float*)(ws + 557056);
  float s = 0.f;
#pragma unroll
  for (int j = 0; j < 16; j++) s += shadow[(j << 9) + t];
  float avg = fmaxf(s * (1.0f / 32768.0f), 1e-10f);
  float term = avg * __logf(avg + 1e-10f);
#pragma unroll
  for (int mm = 1; mm < 64; mm <<= 1) term += __shfl_xor(term, mm, 64);
  if ((t & 63) == 0) red[t >> 6] = term;
  __syncthreads();
  if (t == 0) {
    float H = 0.f;
#pragma unroll
    for (int i = 0; i < 8; i++) H += red[i];
    const float perpl = __expf(-H);
    const float kq = fminf(fmaxf(kappa[0], 1e-5f), 1e5f);
    const float loss = (scal[0] + kq * scal[1] - scal[2]) * (1.0f / 32.0f);
    out[8388608] = loss;
    out[8388609] = perpl;
  }
}

extern "C" void kernel_launch(void* const* d_in, const int* in_sizes, int n_in,
                              void* d_out, int out_size, void* d_ws, size_t ws_size,
                              hipStream_t stream) {
  const float* z     = (const float*)d_in[0];
  const float* kappa = (const float*)d_in[1];
  const float* cb    = (const float*)d_in[2];
  const float* gum   = (const float*)d_in[3];
  char* ws = (char*)d_ws;
  float* out = (float*)d_out;
  hipLaunchKernelGGL(vq_prep0, dim3(529),  dim3(64),  0, stream, cb, ws);
  hipLaunchKernelGGL(vq_prep1, dim3(128),  dim3(256), 0, stream, cb, ws);
  hipLaunchKernelGGL(vq_main,  dim3(2048), dim3(128), 0, stream, z, kappa, gum, ws, out);
  hipLaunchKernelGGL(vq_final, dim3(1),    dim3(512), 0, stream, kappa, ws, out);
}